// Round 16
// baseline (491.165 us; speedup 1.0000x reference)
//
#include <hip/hip_runtime.h>
#include <hip/hip_bf16.h>

typedef unsigned short u16;
typedef float f32x4 __attribute__((ext_vector_type(4)));
typedef short bf16x8 __attribute__((ext_vector_type(8)));
typedef __attribute__((address_space(3))) u16 lds_u16;
typedef __attribute__((address_space(3))) float lds_f32;

#define DEV __device__ __forceinline__

DEV float btof(u16 u) { return __uint_as_float(((unsigned)u) << 16); }
DEV u16 f2b(float f) {                      // RNE fp32 -> bf16 (finite values)
  unsigned u = __float_as_uint(f);
  return (u16)((u + 0x7fffu + ((u >> 16) & 1u)) >> 16);
}
DEV void gld16(const void* g, lds_u16* l) { // async global->LDS, 16B per lane
  __builtin_amdgcn_global_load_lds(
      (const __attribute__((address_space(1))) void*)g,
      (__attribute__((address_space(3))) void*)l, 16, 0, 0);
}
// gelu(x) ~= x * sigmoid(2u), u = x*(0.79788456 + 0.03567741 x^2).  7 VALU.
DEV float gelu_fast(float x) {
  float xx = x * x;
  float p = fmaf(xx, -0.10294357f, -2.3022077f);
  float e; asm("v_exp_f32 %0, %1" : "=v"(e) : "v"(p * x));
  float r; asm("v_rcp_f32 %0, %1" : "=v"(r) : "v"(1.0f + e));
  return x * r;
}

#define LDSV(p) (*(const __attribute__((address_space(3))) bf16x8*)(p))

// ---------------------------------------------------------------------------
// Engine body (r13 config: 16x16x32 MFMA, zero bank conflicts, depth-2
// prefetch, counted vmcnt, 2 barriers/tile).  BM = MR*32, N-tile 256,
// BK=32; LDS ring of 4 bufs x (A[BM][32]+B[256][32]).
// EPI: 3 store bf16 | 4 gelu(acc+bias) bf16 | 5 acc+bias+res_bf16 -> f32
//      6 row-sum-of-squares atomic | 7 stash f32 C[128][256] into LDS base
// ---------------------------------------------------------------------------
template <int EPI, int MR>
DEV void gemm_body(lds_u16* LDS, int bx, int by, long z,
                   const u16* __restrict__ A, long lda,
                   const u16* __restrict__ B, long ldb,
                   void* __restrict__ Cv, long ldc, int K,
                   long sA, long sB, long sC,
                   const float* __restrict__ aux1,
                   const void* __restrict__ aux2)
{
  constexpr int SLOT = MR * 1024 + 8192;
  const int tid = threadIdx.x;
  const int lane = tid & 63, wid = tid >> 6;
  const int wm = wid >> 2, wn = wid & 3;
  const int qr = lane >> 4, qc = lane & 15;

  const long m0 = (long)by * (MR * 32), n0 = (long)bx << 8;
  const u16* Ab = A + z * sA;
  const u16* Bb = B + z * sB;
  const int T = K >> 5;           // K-tiles of 32 (multiple of 4 here)

  f32x4 acc[MR][4];
#pragma unroll
  for (int m = 0; m < MR; ++m)
#pragma unroll
    for (int n = 0; n < 4; ++n) acc[m][n] = (f32x4){0.f, 0.f, 0.f, 0.f};

  // B chunks (256 rows always): 2 x 16B per thread
  const int cb0 = wid * 128 + lane, cb1 = cb0 + 64;
  const int rb0 = cb0 >> 2, rb1 = cb1 >> 2;
  const int kb0off = ((cb0 & 3) ^ ((rb0 >> 1) & 3)) << 3;
  const int kb1off = ((cb1 & 3) ^ ((rb1 >> 1) & 3)) << 3;
  const u16* pb0 = Bb + (n0 + rb0) * ldb + kb0off;
  const u16* pb1 = Bb + (n0 + rb1) * ldb + kb1off;
  const int eb0 = cb0 * 8, eb1 = cb1 * 8;

  // A chunks: MR*128 chunks of 16B; MR==8: 2/thread, MR==4: 1/thread
  const int ca0 = (MR == 8) ? (wid * 128 + lane) : (wid * 64 + lane);
  const int ca1 = ca0 + 64;
  const int ra0 = ca0 >> 2, ra1 = ca1 >> 2;
  const int ka0off = ((ca0 & 3) ^ ((ra0 >> 1) & 3)) << 3;
  const int ka1off = ((ca1 & 3) ^ ((ra1 >> 1) & 3)) << 3;
  const u16* pa0 = Ab + (m0 + ra0) * lda + ka0off;
  const u16* pa1 = (MR == 8) ? (Ab + (m0 + ra1) * lda + ka1off) : pa0;
  const int ea0 = ca0 * 8, ea1 = ca1 * 8;

  const int swz = (qr ^ ((qc >> 1) & 3)) << 3;

  auto stageA = [&](int bsel, int so) {
    gld16(pa0 + so, LDS + bsel * SLOT + ea0);
    if constexpr (MR == 8) gld16(pa1 + so, LDS + bsel * SLOT + ea1);
  };
  auto stageB = [&](int bsel, int so) {
    gld16(pb0 + so, LDS + bsel * SLOT + MR * 1024 + eb0);
    gld16(pb1 + so, LDS + bsel * SLOT + MR * 1024 + eb1);
  };
  auto ldA4 = [&](bf16x8* dst, int bsel, int mh) {
#pragma unroll
    for (int mm = 0; mm < 4; ++mm) {
      const int rr = wm * (MR * 16) + (mh * 4 + mm) * 16 + qc;
      dst[mm] = LDSV(LDS + bsel * SLOT + rr * 32 + swz);
    }
  };
  auto ldB4 = [&](bf16x8* dst, int bsel) {
#pragma unroll
    for (int n = 0; n < 4; ++n) {
      const int rr = wn * 64 + n * 16 + qc;
      dst[n] = LDSV(LDS + bsel * SLOT + MR * 1024 + rr * 32 + swz);
    }
  };

  // prologue: stage tiles 0 and 1; pointers then at tile 2
  stageA(0, 0);  stageB(0, 0);
  stageA(1, 32); stageB(1, 32);
  pa0 += 64; pa1 += 64; pb0 += 64; pb1 += 64;

#define WAITV(N) asm volatile("s_waitcnt vmcnt(" #N ")" ::: "memory")
#define MFMAQ(MB) \
    __builtin_amdgcn_s_setprio(1); \
    _Pragma("unroll") \
    for (int mm = 0; mm < 4; ++mm) \
      _Pragma("unroll") \
      for (int n = 0; n < 4; ++n) \
        acc[MB + mm][n] = __builtin_amdgcn_mfma_f32_16x16x32_bf16( \
            a4[mm], b4[n], acc[MB + mm][n], 0, 0, 0); \
    __builtin_amdgcn_s_setprio(0);

#define TILE32(BUF, PF1, PF2, SO) { \
    bf16x8 a4[4], b4[4]; \
    if (PF2) { stageA((BUF + 2) & 3, SO); stageB((BUF + 2) & 3, SO); \
               if constexpr (MR == 8) { WAITV(8); } else { WAITV(6); } } \
    else if (PF1) { if constexpr (MR == 8) { WAITV(4); } else { WAITV(3); } } \
    else { WAITV(0); } \
    __builtin_amdgcn_s_barrier(); \
    ldA4(a4, BUF, 0); ldB4(b4, BUF); \
    MFMAQ(0) \
    if constexpr (MR == 8) { \
      ldA4(a4, BUF, 1); \
      MFMAQ(4) \
    } \
    asm volatile("s_waitcnt lgkmcnt(0)" ::: "memory"); \
    __builtin_amdgcn_s_barrier(); }

  for (int t2 = 0; t2 < T; t2 += 4) {
    const bool pfn = (t2 + 4 < T);
    TILE32(0, true, true, 0)
    TILE32(1, true, true, 32)
    TILE32(2, true, pfn, 64)
    TILE32(3, pfn, pfn, 96)
    pa0 += 128; pa1 += 128; pb0 += 128; pb1 += 128;
  }
#undef TILE32
#undef MFMAQ
#undef WAITV

  // epilogue: C/D layout col=lane&15, row=(lane>>4)*4+reg
  if constexpr (EPI == 6) {
    float* rsc2 = (float*)Cv;
#pragma unroll
    for (int m = 0; m < MR; ++m)
#pragma unroll
      for (int j = 0; j < 4; ++j) {
        float s = 0.f;
#pragma unroll
        for (int n = 0; n < 4; ++n) { float t2 = acc[m][n][j]; s = fmaf(t2, t2, s); }
        s += __shfl_xor(s, 1); s += __shfl_xor(s, 2);
        s += __shfl_xor(s, 4); s += __shfl_xor(s, 8);
        if (qc == 0)
          atomicAdd(rsc2 + (m0 + wm * (MR * 16) + m * 16 + qr * 4 + j), s);
      }
  } else if constexpr (EPI == 7) {
    // stash raw sim into LDS C[128][256] f32 (ring is dead; sealed above)
    lds_f32* C = (lds_f32*)LDS;
#pragma unroll
    for (int m = 0; m < MR; ++m)
#pragma unroll
      for (int n = 0; n < 4; ++n) {
        const int row0 = wm * 64 + m * 16 + qr * 4;
        const int col = wn * 64 + n * 16 + qc;
#pragma unroll
        for (int j = 0; j < 4; ++j)
          C[(row0 + j) * 256 + col] = acc[m][n][j];
      }
  } else {
#pragma unroll
    for (int m = 0; m < MR; ++m) {
#pragma unroll
      for (int n = 0; n < 4; ++n) {
        const long row0 = m0 + wm * (MR * 16) + m * 16 + qr * 4;
        const long col = n0 + wn * 64 + n * 16 + qc;
#pragma unroll
        for (int j = 0; j < 4; ++j) {
          const long idx = z * sC + (row0 + j) * ldc + col;
          float val = acc[m][n][j];
          if constexpr (EPI == 3) ((u16*)Cv)[idx] = f2b(val);
          else if constexpr (EPI == 4)
            ((u16*)Cv)[idx] = f2b(gelu_fast(val + aux1[col]));
          else if constexpr (EPI == 5) {
            float r = btof(((const u16*)aux2)[idx]);
            ((float*)Cv)[idx] = val + aux1[col] + r;
          }
        }
      }
    }
  }
}

// ---------------------------------------------------------------------------
// standalone wrapper (FF1 / FF2): XCD-swizzled grid + static LDS
// __launch_bounds__(512,2): arg2=min blocks/CU -> VGPR cap 128 (r7 lesson).
// ---------------------------------------------------------------------------
template <int EPI, int MR>
__global__ __launch_bounds__(512, 2) void gemm256(
    const u16* __restrict__ A, long lda, const u16* __restrict__ B, long ldb,
    void* __restrict__ Cv, long ldc, int K, long sA, long sB, long sC,
    const float* __restrict__ aux1, const void* __restrict__ aux2)
{
  __shared__ u16 lds[4 * (MR * 1024 + 8192)];
  const int gx = gridDim.x, gy = gridDim.y;
  const int nwg = gx * gy * (int)gridDim.z;
  const int orig = blockIdx.x + gx * (blockIdx.y + gy * blockIdx.z);
  const int nid = (orig & 7) * (nwg >> 3) + (orig >> 3);
  const int bx = nid % gx;
  const int rem1 = nid / gx;
  const int by = rem1 % gy;
  const long z = rem1 / gy;
  gemm_body<EPI, MR>((lds_u16*)lds, bx, by, z, A, lda, B, ldb, Cv, ldc, K,
                     sA, sB, sC, aux1, aux2);
}

// ---------------------------------------------------------------------------
// mid1: qnorm (256 blocks) + v-gemm (16 blocks).  Must complete before
// sim_topk (which reads rsc2 and vb) -> separate dispatch, no in-dispatch
// ordering assumption.
// ---------------------------------------------------------------------------
__global__ __launch_bounds__(512, 2) void mid1(
    const u16* __restrict__ x3, const u16* __restrict__ WqT,
    float* __restrict__ rsc2, const u16* __restrict__ tb,
    const u16* __restrict__ WvT, u16* __restrict__ vb)
{
  __shared__ u16 slds[4 * (8 * 1024 + 8192)];   // 128 KiB
  lds_u16* L = (lds_u16*)slds;
  const int bid = blockIdx.x;
  if (bid < 256) {
    const int nid = ((bid & 7) << 5) + (bid >> 3);
    gemm_body<6, 8>(L, nid & 1, nid >> 1, 0, x3, 1536, WqT, 512, rsc2, 1,
                    512, 0, 0, 0, nullptr, nullptr);
  } else {
    const int l = bid - 256;
    const int nid = ((l & 7) << 1) + (l >> 3);
    gemm_body<3, 8>(L, nid & 1, nid >> 1, 0, tb, 512, WvT, 512, vb, 512,
                    512, 0, 0, 0, nullptr, nullptr);
  }
}

// ---------------------------------------------------------------------------
// sim_topk: 256 blocks.  Main loop = sim GEMM (K=1536, MR4) with EPI7 LDS
// stash; then each of 8 waves processes 16 rows: top-8 select (+fp64 rescue
// if gap(5,6) < 2e-4), softmax, v-gather, gate, residual, LN2 -> yb.
// LDS: union of 96KB ring and 128KB C-stash (ring dead after sealed loop).
// ---------------------------------------------------------------------------
__global__ __launch_bounds__(512, 2) void sim_topk(
    const u16* __restrict__ x3, const u16* __restrict__ wA,
    const u16* __restrict__ vb, const u16* __restrict__ xr2,
    const float* __restrict__ gate, const double* __restrict__ wtmpT,
    const float* __restrict__ rsc2, const float* __restrict__ ls,
    const float* __restrict__ g2, const float* __restrict__ b2,
    u16* __restrict__ yb)
{
  __shared__ u16 slds[65536];                   // 128 KiB (ring 96K | C 128K)
  lds_u16* L = (lds_u16*)slds;
  const int bid = blockIdx.x;
  const int nid = ((bid & 7) << 5) + (bid >> 3);
  const int by = nid & 31;
  const long zb = nid >> 5;

  gemm_body<7, 4>(L, 0, by, zb, x3, 1536, wA, 1536, nullptr, 0, 1536,
                  4096L * 1536, 256L * 1536, 0, nullptr, nullptr);
  __syncthreads();                              // stash complete

  const lds_f32* C = (const lds_f32*)L;
  const int lane = threadIdx.x & 63, wid = threadIdx.x >> 6;

  float g2r[8], b2r[8];
  *(float4*)&g2r[0] = *(const float4*)(g2 + lane * 8);
  *(float4*)&g2r[4] = *(const float4*)(g2 + lane * 8 + 4);
  *(float4*)&b2r[0] = *(const float4*)(b2 + lane * 8);
  *(float4*)&b2r[4] = *(const float4*)(b2 + lane * 8 + 4);
  const float lsv = __expf(ls[0]) * 0.044194173824159223f;
  const int b = (int)zb;

  for (int ir = 0; ir < 16; ++ir) {
    const int r = wid * 16 + ir;
    const long grow = zb * 4096 + by * 128 + r;

    const u16* xr = x3 + grow * 1536 + lane * 8;
    bf16x8 a0 = *(const bf16x8*)xr;
    bf16x8 a1 = *(const bf16x8*)(xr + 512);
    float xv[8];
#pragma unroll
    for (int j = 0; j < 8; ++j) xv[j] = btof((u16)a0[j]) + btof((u16)a1[j]);

    float vals[4];
#pragma unroll
    for (int i = 0; i < 4; ++i) vals[i] = C[r * 256 + lane + 64 * i];

    float topv[8]; int topi[8];
#pragma unroll
    for (int m = 0; m < 8; ++m) {
      float bv = vals[0]; int bl = 0;
      if (vals[1] > bv) { bv = vals[1]; bl = 1; }
      if (vals[2] > bv) { bv = vals[2]; bl = 2; }
      if (vals[3] > bv) { bv = vals[3]; bl = 3; }
      int bi = (bl << 6) | lane;       // token index = 64*bl + lane
#pragma unroll
      for (int off = 32; off; off >>= 1) {
        float ov = __shfl_xor(bv, off);
        int oi = __shfl_xor(bi, off);
        if (ov > bv || (ov == bv && oi < bi)) { bv = ov; bi = oi; }
      }
      topv[m] = bv; topi[m] = bi;
      if ((bi & 63) == lane) vals[bi >> 6] = -INFINITY;
    }

    if (topv[4] - topv[5] < 2e-4f) { // wave-uniform: fp64 re-rank of top-8
      bf16x8 a2 = *(const bf16x8*)(xr2 + grow * 512 + lane * 8);
      double xd[8];
#pragma unroll
      for (int j = 0; j < 8; ++j)
        xd[j] = (double)btof((u16)a0[j]) + (double)btof((u16)a1[j]) +
                (double)btof((u16)a2[j]);
      double cv[8]; int ti[8];
#pragma unroll
      for (int m = 0; m < 8; ++m) {
        const double* wp = wtmpT + ((long)b * 256 + topi[m]) * 512 + lane * 8;
        double a = 0.0;
#pragma unroll
        for (int j = 0; j < 8; ++j) a += xd[j] * wp[j];
#pragma unroll
        for (int off = 32; off; off >>= 1) a += __shfl_xor(a, off);
        cv[m] = a; ti[m] = topi[m];
      }
#define CE(i, jj) { \
      bool sw = (cv[jj] > cv[i]) || (cv[jj] == cv[i] && ti[jj] < ti[i]); \
      double tv = cv[i]; int tix = ti[i]; \
      cv[i] = sw ? cv[jj] : cv[i];  ti[i] = sw ? ti[jj] : ti[i]; \
      cv[jj] = sw ? tv : cv[jj];    ti[jj] = sw ? tix : ti[jj]; }
      CE(0,1) CE(2,3) CE(4,5) CE(6,7)
      CE(0,2) CE(1,3) CE(4,6) CE(5,7)
      CE(1,2) CE(5,6)
      CE(0,4) CE(1,5) CE(2,6) CE(3,7)
      CE(2,4) CE(3,5)
      CE(1,2) CE(3,4) CE(5,6)
#undef CE
#pragma unroll
      for (int m = 0; m < 5; ++m) { topv[m] = (float)cv[m]; topi[m] = ti[m]; }
    }

    const float rs = lsv * rsqrtf(rsc2[grow]);
    float e[5], se = 0.f;
#pragma unroll
    for (int m = 0; m < 5; ++m) {
      e[m] = __expf((topv[m] - topv[0]) * rs); se += e[m];
    }
    const float inv = 1.0f / se;
    const float g = gate[grow];

    float acc8[8] = {0, 0, 0, 0, 0, 0, 0, 0};
#pragma unroll
    for (int m = 0; m < 5; ++m) {
      const u16* vr = vb + ((long)b * 256 + topi[m]) * 512 + lane * 8;
      bf16x8 vv = *(const bf16x8*)vr;
      float wgt = e[m] * inv;
#pragma unroll
      for (int j = 0; j < 8; ++j) acc8[j] += wgt * btof((u16)vv[j]);
    }

    float y8[8]; float s = 0.f, sq = 0.f;
#pragma unroll
    for (int j = 0; j < 8; ++j) {
      y8[j] = xv[j] + acc8[j] * g;
      s += y8[j]; sq += y8[j] * y8[j];
    }
#pragma unroll
    for (int off = 32; off; off >>= 1) { s += __shfl_xor(s, off); sq += __shfl_xor(sq, off); }
    const float mu = s * (1.f / 512.f);
    const float var = sq * (1.f / 512.f) - mu * mu;
    const float rstd = 1.0f / sqrtf(var + 1e-5f);

    bf16x8 outp;
#pragma unroll
    for (int j = 0; j < 8; ++j)
      outp[j] = (short)f2b((y8[j] - mu) * rstd * g2r[j] + b2r[j]);
    *(bf16x8*)(yb + grow * 512 + lane * 8) = outp;
  }
}

// ---------------------------------------------------------------------------
// prep: one dispatch fusing
//   [0,640):      fp32->bf16 transposed weight copies (Wq,Wv,W1,W2)
//   [640,8832):   LN1 -> x3=[x0|x1|x0], xr2, gate
//   [8832,9344):  k-quantize -> tb (bf16 text; v-gemm input)
//   9344:         zero rsc2
//   [9345,10369): wtilde: w~ = Wq @ (text/||text||)^T in fp64 -> wA + wtmpT
//                 (norm folded out of the dot: (Wq . text) / ||text||)
// ---------------------------------------------------------------------------
__global__ __launch_bounds__(256) void prep_kernel(
    const float* __restrict__ vis, const float* __restrict__ text,
    const float* __restrict__ g1, const float* __restrict__ b1,
    const float* __restrict__ Wg, const float* __restrict__ bg,
    const float* __restrict__ Wq, const float* __restrict__ Wv,
    const float* __restrict__ W1, const float* __restrict__ W2,
    u16* __restrict__ x3, u16* __restrict__ xr2, float* __restrict__ gate,
    u16* __restrict__ tb, u16* __restrict__ WqT, u16* __restrict__ WvT,
    u16* __restrict__ W1T, u16* __restrict__ W2T, float* __restrict__ rsc2,
    u16* __restrict__ wA, double* __restrict__ wtmpT)
{
  const int bid = blockIdx.x;
  const int lane = threadIdx.x & 63, wv = threadIdx.x >> 6;

  if (bid < 640) {                      // ---- weight transposes ----
    const float* src; u16* dst; int R, C, id, tilesX;
    if (bid < 64)       { src = Wq; dst = WqT; R = 512;  C = 512;  id = bid;       tilesX = 8; }
    else if (bid < 128) { src = Wv; dst = WvT; R = 512;  C = 512;  id = bid - 64;  tilesX = 8; }
    else if (bid < 384) { src = W1; dst = W1T; R = 512;  C = 2048; id = bid - 128; tilesX = 32; }
    else                { src = W2; dst = W2T; R = 2048; C = 512;  id = bid - 384; tilesX = 8; }
    const int c0 = (id % tilesX) * 64, r0 = (id / tilesX) * 64;
    __shared__ float t[64][65];
    const int tx = threadIdx.x & 63, ty = threadIdx.x >> 6;
    for (int j = ty; j < 64; j += 4)
      t[j][tx] = src[(long)(r0 + j) * C + c0 + tx];
    __syncthreads();
    for (int j = ty; j < 64; j += 4)
      dst[(long)(c0 + j) * R + r0 + tx] = f2b(t[tx][j]);
    return;
  }

  if (bid < 8832) {                     // ---- LN1 ----
    const long row = (long)(bid - 640) * 4 + wv;
    const float* src = vis + row * 512 + lane * 8;
    float v[8];
    *(float4*)&v[0] = *(const float4*)src;
    *(float4*)&v[4] = *(const float4*)(src + 4);
    float s = 0.f, sq = 0.f;
#pragma unroll
    for (int j = 0; j < 8; ++j) { s += v[j]; sq += v[j] * v[j]; }
#pragma unroll
    for (int off = 32; off; off >>= 1) { s += __shfl_xor(s, off); sq += __shfl_xor(sq, off); }
    const float mu = s * (1.f / 512.f);
    const float var = sq * (1.f / 512.f) - mu * mu;
    const float rstd = 1.0f / sqrtf(var + 1e-5f);

    float g1r[8], b1r[8], wgr[8];
    *(float4*)&g1r[0] = *(const float4*)(g1 + lane * 8);
    *(float4*)&g1r[4] = *(const float4*)(g1 + lane * 8 + 4);
    *(float4*)&b1r[0] = *(const float4*)(b1 + lane * 8);
    *(float4*)&b1r[4] = *(const float4*)(b1 + lane * 8 + 4);
    *(float4*)&wgr[0] = *(const float4*)(Wg + lane * 8);
    *(float4*)&wgr[4] = *(const float4*)(Wg + lane * 8 + 4);

    bf16x8 p0, p1, p2;
    float gd = 0.f;
#pragma unroll
    for (int j = 0; j < 8; ++j) {
      float d = (v[j] - mu) * rstd * g1r[j] + b1r[j];
      gd += d * wgr[j];
      u16 h0 = f2b(d);        float r1 = d - btof(h0);
      u16 h1 = f2b(r1);       float r2 = r1 - btof(h1);
      u16 h2 = f2b(r2);
      p0[j] = (short)h0; p1[j] = (short)h1; p2[j] = (short)h2;
    }
#pragma unroll
    for (int off = 32; off; off >>= 1) gd += __shfl_xor(gd, off);
    if (lane == 0) gate[row] = 1.0f / (1.0f + __expf(-(gd + bg[0])));

    u16* dst = x3 + row * 1536 + lane * 8;
    *(bf16x8*)dst = p0;
    *(bf16x8*)(dst + 512) = p1;
    *(bf16x8*)(dst + 1024) = p0;        // duplicate limb0 for sim K=1536
    *(bf16x8*)(xr2 + row * 512 + lane * 8) = p2;
    return;
  }

  if (bid < 9344) {                     // ---- text -> bf16 tb ----
    const long row = (long)(bid - 8832) * 4 + wv;   // 0..2047
    const float* src = text + row * 512 + lane * 8;
    float v[8];
    *(float4*)&v[0] = *(const float4*)src;
    *(float4*)&v[4] = *(const float4*)(src + 4);
    bf16x8 pt;
#pragma unroll
    for (int j = 0; j < 8; ++j) pt[j] = (short)f2b(v[j]);
    *(bf16x8*)(tb + row * 512 + lane * 8) = pt;
    return;
  }

  if (bid == 9344) {                    // ---- zero rsc2 ----
    rsc2[threadIdx.x] = 0.f;
    rsc2[256 + threadIdx.x] = 0.f;
    return;
  }

  // ---- wtilde: blocks [9345, 10369) ----
  {
    const int id = bid - 9345;
    const int c0 = (id & 127) * 4;      // Wq row group
    const int b = id >> 7;              // batch
    __shared__ float wrow[4][512];
#pragma unroll
    for (int i = 0; i < 8; ++i) {
      int idx = threadIdx.x + i * 256;
      wrow[idx >> 9][idx & 511] = Wq[(long)c0 * 512 + idx];
    }
    __syncthreads();
    const int tok = threadIdx.x;
    const float* tr = text + ((long)b * 256 + tok) * 512;
    double a[4] = {0, 0, 0, 0};
    float ss = 0.f;
    for (int j = 0; j < 512; j += 4) {
      float4 tv = *(const float4*)(tr + j);
      ss += tv.x * tv.x + tv.y * tv.y + tv.z * tv.z + tv.w * tv.w;
#pragma unroll
      for (int i = 0; i < 4; ++i) {
        a[i] += (double)wrow[i][j] * (double)tv.x;
        a[i] += (double)wrow[i][j + 1] * (double)tv.y;
        a[i] += (double)wrow[i][j + 2] * (double)tv.z;
        a[i] += (double)wrow[i][j + 3] * (double)tv.w;
      }
    }
    const double rsn = 1.0 / sqrt((double)ss);
    const long kb = (long)b * 256 + tok;
#pragma unroll
    for (int i = 0; i < 4; ++i) {
      const int c = c0 + i;
      double av = a[i] * rsn;
      u16 h0 = f2b((float)av);  double r1 = av - (double)btof(h0);
      u16 h1 = f2b((float)r1);
      wA[kb * 1536 + c] = h0;
      wA[kb * 1536 + 512 + c] = h0;
      wA[kb * 1536 + 1024 + c] = h1;
      wtmpT[kb * 512 + c] = av;
    }
  }
}

// ---------------------------------------------------------------------------
extern "C" void kernel_launch(void* const* d_in, const int* in_sizes, int n_in,
                              void* d_out, int out_size, void* d_ws,
                              size_t ws_size, hipStream_t stream)
{
  const float* vis  = (const float*)d_in[0];
  const float* text = (const float*)d_in[1];
  const float* g1   = (const float*)d_in[2];
  const float* b1   = (const float*)d_in[3];
  const float* g2   = (const float*)d_in[4];
  const float* b2   = (const float*)d_in[5];
  const float* Wq   = (const float*)d_in[6];
  const float* Wv   = (const float*)d_in[7];
  const float* ls   = (const float*)d_in[8];
  const float* Wg   = (const float*)d_in[9];
  const float* bg   = (const float*)d_in[10];
  const float* W1   = (const float*)d_in[11];
  const float* bff1 = (const float*)d_in[12];
  const float* W2   = (const float*)d_in[13];
  const float* bff2 = (const float*)d_in[14];
  (void)in_sizes; (void)n_in; (void)out_size; (void)ws_size;

  char* w = (char*)d_ws;
  auto alloc = [&](size_t bytes) {
    char* p = w; w += (bytes + 255) & ~(size_t)255; return p;
  };
  u16* x3 = (u16*)alloc(134217728);
  u16* h = x3;
  char* gap = (char*)x3 + 100663296;            // 33.5MB free until FF1
  double* wtmpT = (double*)gap;                 // 8.4MB  [prep -> sim_topk]
  u16* wA = (u16*)(gap + 8388608);              // 6.3MB  [prep -> sim_topk]
  u16* yb = (u16*)alloc(33554432);
  u16* xr2 = (u16*)alloc(33554432);
  u16* tb = (u16*)alloc(2097152);
  u16* vb = (u16*)alloc(2097152);
  u16* WqT = (u16*)alloc(524288);
  u16* WvT = (u16*)alloc(524288);
  u16* W1T = (u16*)alloc(2097152);
  u16* W2T = (u16*)alloc(2097152);
  float* gate = (float*)alloc(131072);
  float* rsc2 = (float*)alloc(131072);

  dim3 b256(256), b512(512);

  // prep: transposes + LN1 + tb + rsc2 zero + wtilde (one dispatch)
  prep_kernel<<<10369, b256, 0, stream>>>(vis, text, g1, b1, Wg, bg, Wq, Wv,
                                          W1, W2, x3, xr2, gate, tb, WqT,
                                          WvT, W1T, W2T, rsc2, wA, wtmpT);

  // mid1: qnorm (256) + v-gemm (16) — completes rsc2/vb before sim_topk
  mid1<<<272, b512, 0, stream>>>(x3, WqT, rsc2, tb, WvT, vb);

  // sim GEMM fused with top-k/softmax/gather/LN2 -> yb
  sim_topk<<<256, b512, 0, stream>>>(x3, wA, vb, xr2, gate, wtmpT, rsc2, ls,
                                     g2, b2, yb);

  // FF1: h = gelu(y @ W1^T + bff1)  M=32768 N=2048 K=512
  gemm256<4, 8><<<dim3(8, 128, 1), b512, 0, stream>>>(
      yb, 512, W1T, 512, h, 2048, 512, 0, 0, 0, bff1, nullptr);
  // FF2: out = h @ W2^T + bff2 + y  M=32768 N=512 K=2048 -> fp32 d_out
  gemm256<5, 8><<<dim3(2, 128, 1), b512, 0, stream>>>(
      h, 2048, W2T, 2048, d_out, 512, 2048, 0, 0, 0, bff2, yb);
}

// Round 17
// 413.888 us; speedup vs baseline: 1.1867x; 1.1867x over previous
//
#include <hip/hip_runtime.h>
#include <hip/hip_bf16.h>

typedef unsigned short u16;
typedef float f32x4 __attribute__((ext_vector_type(4)));
typedef short bf16x8 __attribute__((ext_vector_type(8)));
typedef __attribute__((address_space(3))) u16 lds_u16;
typedef __attribute__((address_space(3))) float lds_f32;

#define DEV __device__ __forceinline__

DEV float btof(u16 u) { return __uint_as_float(((unsigned)u) << 16); }
DEV u16 f2b(float f) {                      // RNE fp32 -> bf16 (finite values)
  unsigned u = __float_as_uint(f);
  return (u16)((u + 0x7fffu + ((u >> 16) & 1u)) >> 16);
}
DEV void gld16(const void* g, lds_u16* l) { // async global->LDS, 16B per lane
  __builtin_amdgcn_global_load_lds(
      (const __attribute__((address_space(1))) void*)g,
      (__attribute__((address_space(3))) void*)l, 16, 0, 0);
}
// gelu(x) ~= x * sigmoid(2u), u = x*(0.79788456 + 0.03567741 x^2).  7 VALU.
DEV float gelu_fast(float x) {
  float xx = x * x;
  float p = fmaf(xx, -0.10294357f, -2.3022077f);
  float e; asm("v_exp_f32 %0, %1" : "=v"(e) : "v"(p * x));
  float r; asm("v_rcp_f32 %0, %1" : "=v"(r) : "v"(1.0f + e));
  return x * r;
}

#define LDSV(p) (*(const __attribute__((address_space(3))) bf16x8*)(p))

// ---------------------------------------------------------------------------
// Engine body (r13 config: 16x16x32 MFMA, zero bank conflicts, depth-2
// prefetch, counted vmcnt, 2 barriers/tile).  BM = MR*32, N-tile 256,
// BK=32; LDS ring of 4 bufs x (A[BM][32]+B[256][32]).
// EPI: 3 store bf16 | 4 gelu(acc+bias) bf16 | 5 acc+bias+res_bf16 -> f32
//      6 row-sum-of-squares atomic | 7 stash f32 C[128][256] into LDS base
// ---------------------------------------------------------------------------
template <int EPI, int MR>
DEV void gemm_body(lds_u16* LDS, int bx, int by, long z,
                   const u16* __restrict__ A, long lda,
                   const u16* __restrict__ B, long ldb,
                   void* __restrict__ Cv, long ldc, int K,
                   long sA, long sB, long sC,
                   const float* __restrict__ aux1,
                   const void* __restrict__ aux2)
{
  constexpr int SLOT = MR * 1024 + 8192;
  const int tid = threadIdx.x;
  const int lane = tid & 63, wid = tid >> 6;
  const int wm = wid >> 2, wn = wid & 3;
  const int qr = lane >> 4, qc = lane & 15;

  const long m0 = (long)by * (MR * 32), n0 = (long)bx << 8;
  const u16* Ab = A + z * sA;
  const u16* Bb = B + z * sB;
  const int T = K >> 5;           // K-tiles of 32 (multiple of 4 here)

  f32x4 acc[MR][4];
#pragma unroll
  for (int m = 0; m < MR; ++m)
#pragma unroll
    for (int n = 0; n < 4; ++n) acc[m][n] = (f32x4){0.f, 0.f, 0.f, 0.f};

  // B chunks (256 rows always): 2 x 16B per thread
  const int cb0 = wid * 128 + lane, cb1 = cb0 + 64;
  const int rb0 = cb0 >> 2, rb1 = cb1 >> 2;
  const int kb0off = ((cb0 & 3) ^ ((rb0 >> 1) & 3)) << 3;
  const int kb1off = ((cb1 & 3) ^ ((rb1 >> 1) & 3)) << 3;
  const u16* pb0 = Bb + (n0 + rb0) * ldb + kb0off;
  const u16* pb1 = Bb + (n0 + rb1) * ldb + kb1off;
  const int eb0 = cb0 * 8, eb1 = cb1 * 8;

  // A chunks: MR*128 chunks of 16B; MR==8: 2/thread, MR==4: 1/thread
  const int ca0 = (MR == 8) ? (wid * 128 + lane) : (wid * 64 + lane);
  const int ca1 = ca0 + 64;
  const int ra0 = ca0 >> 2, ra1 = ca1 >> 2;
  const int ka0off = ((ca0 & 3) ^ ((ra0 >> 1) & 3)) << 3;
  const int ka1off = ((ca1 & 3) ^ ((ra1 >> 1) & 3)) << 3;
  const u16* pa0 = Ab + (m0 + ra0) * lda + ka0off;
  const u16* pa1 = (MR == 8) ? (Ab + (m0 + ra1) * lda + ka1off) : pa0;
  const int ea0 = ca0 * 8, ea1 = ca1 * 8;

  const int swz = (qr ^ ((qc >> 1) & 3)) << 3;

  auto stageA = [&](int bsel, int so) {
    gld16(pa0 + so, LDS + bsel * SLOT + ea0);
    if constexpr (MR == 8) gld16(pa1 + so, LDS + bsel * SLOT + ea1);
  };
  auto stageB = [&](int bsel, int so) {
    gld16(pb0 + so, LDS + bsel * SLOT + MR * 1024 + eb0);
    gld16(pb1 + so, LDS + bsel * SLOT + MR * 1024 + eb1);
  };
  auto ldA4 = [&](bf16x8* dst, int bsel, int mh) {
#pragma unroll
    for (int mm = 0; mm < 4; ++mm) {
      const int rr = wm * (MR * 16) + (mh * 4 + mm) * 16 + qc;
      dst[mm] = LDSV(LDS + bsel * SLOT + rr * 32 + swz);
    }
  };
  auto ldB4 = [&](bf16x8* dst, int bsel) {
#pragma unroll
    for (int n = 0; n < 4; ++n) {
      const int rr = wn * 64 + n * 16 + qc;
      dst[n] = LDSV(LDS + bsel * SLOT + MR * 1024 + rr * 32 + swz);
    }
  };

  // prologue: stage tiles 0 and 1; pointers then at tile 2
  stageA(0, 0);  stageB(0, 0);
  stageA(1, 32); stageB(1, 32);
  pa0 += 64; pa1 += 64; pb0 += 64; pb1 += 64;

#define WAITV(N) asm volatile("s_waitcnt vmcnt(" #N ")" ::: "memory")
#define MFMAQ(MB) \
    __builtin_amdgcn_s_setprio(1); \
    _Pragma("unroll") \
    for (int mm = 0; mm < 4; ++mm) \
      _Pragma("unroll") \
      for (int n = 0; n < 4; ++n) \
        acc[MB + mm][n] = __builtin_amdgcn_mfma_f32_16x16x32_bf16( \
            a4[mm], b4[n], acc[MB + mm][n], 0, 0, 0); \
    __builtin_amdgcn_s_setprio(0);

#define TILE32(BUF, PF1, PF2, SO) { \
    bf16x8 a4[4], b4[4]; \
    if (PF2) { stageA((BUF + 2) & 3, SO); stageB((BUF + 2) & 3, SO); \
               if constexpr (MR == 8) { WAITV(8); } else { WAITV(6); } } \
    else if (PF1) { if constexpr (MR == 8) { WAITV(4); } else { WAITV(3); } } \
    else { WAITV(0); } \
    __builtin_amdgcn_s_barrier(); \
    ldA4(a4, BUF, 0); ldB4(b4, BUF); \
    MFMAQ(0) \
    if constexpr (MR == 8) { \
      ldA4(a4, BUF, 1); \
      MFMAQ(4) \
    } \
    asm volatile("s_waitcnt lgkmcnt(0)" ::: "memory"); \
    __builtin_amdgcn_s_barrier(); }

  for (int t2 = 0; t2 < T; t2 += 4) {
    const bool pfn = (t2 + 4 < T);
    TILE32(0, true, true, 0)
    TILE32(1, true, true, 32)
    TILE32(2, true, pfn, 64)
    TILE32(3, pfn, pfn, 96)
    pa0 += 128; pa1 += 128; pb0 += 128; pb1 += 128;
  }
#undef TILE32
#undef MFMAQ
#undef WAITV

  // epilogue: C/D layout col=lane&15, row=(lane>>4)*4+reg
  if constexpr (EPI == 6) {
    float* rsc2 = (float*)Cv;
#pragma unroll
    for (int m = 0; m < MR; ++m)
#pragma unroll
      for (int j = 0; j < 4; ++j) {
        float s = 0.f;
#pragma unroll
        for (int n = 0; n < 4; ++n) { float t2 = acc[m][n][j]; s = fmaf(t2, t2, s); }
        s += __shfl_xor(s, 1); s += __shfl_xor(s, 2);
        s += __shfl_xor(s, 4); s += __shfl_xor(s, 8);
        if (qc == 0)
          atomicAdd(rsc2 + (m0 + wm * (MR * 16) + m * 16 + qr * 4 + j), s);
      }
  } else if constexpr (EPI == 7) {
    // stash raw sim into LDS C[128][256] f32 (ring is dead; sealed above)
    lds_f32* C = (lds_f32*)LDS;
#pragma unroll
    for (int m = 0; m < MR; ++m)
#pragma unroll
      for (int n = 0; n < 4; ++n) {
        const int row0 = wm * 64 + m * 16 + qr * 4;
        const int col = wn * 64 + n * 16 + qc;
#pragma unroll
        for (int j = 0; j < 4; ++j)
          C[(row0 + j) * 256 + col] = acc[m][n][j];
      }
  } else {
#pragma unroll
    for (int m = 0; m < MR; ++m) {
#pragma unroll
      for (int n = 0; n < 4; ++n) {
        const long row0 = m0 + wm * (MR * 16) + m * 16 + qr * 4;
        const long col = n0 + wn * 64 + n * 16 + qc;
#pragma unroll
        for (int j = 0; j < 4; ++j) {
          const long idx = z * sC + (row0 + j) * ldc + col;
          float val = acc[m][n][j];
          if constexpr (EPI == 3) ((u16*)Cv)[idx] = f2b(val);
          else if constexpr (EPI == 4)
            ((u16*)Cv)[idx] = f2b(gelu_fast(val + aux1[col]));
          else if constexpr (EPI == 5) {
            float r = btof(((const u16*)aux2)[idx]);
            ((float*)Cv)[idx] = val + aux1[col] + r;
          }
        }
      }
    }
  }
}

// ---------------------------------------------------------------------------
// standalone wrapper (FF1 / FF2): XCD-swizzled grid + static LDS
// __launch_bounds__(512,2): arg2=min blocks/CU -> VGPR cap 128 (r7 lesson).
// ---------------------------------------------------------------------------
template <int EPI, int MR>
__global__ __launch_bounds__(512, 2) void gemm256(
    const u16* __restrict__ A, long lda, const u16* __restrict__ B, long ldb,
    void* __restrict__ Cv, long ldc, int K, long sA, long sB, long sC,
    const float* __restrict__ aux1, const void* __restrict__ aux2)
{
  __shared__ u16 lds[4 * (MR * 1024 + 8192)];
  const int gx = gridDim.x, gy = gridDim.y;
  const int nwg = gx * gy * (int)gridDim.z;
  const int orig = blockIdx.x + gx * (blockIdx.y + gy * blockIdx.z);
  const int nid = (orig & 7) * (nwg >> 3) + (orig >> 3);
  const int bx = nid % gx;
  const int rem1 = nid / gx;
  const int by = rem1 % gy;
  const long z = rem1 / gy;
  gemm_body<EPI, MR>((lds_u16*)lds, bx, by, z, A, lda, B, ldb, Cv, ldc, K,
                     sA, sB, sC, aux1, aux2);
}

// ---------------------------------------------------------------------------
// mid1: qnorm (256 blocks) + v-gemm (16 blocks).  Completes rsc2/vb before
// sim_topk (separate dispatch -> no in-dispatch ordering assumption).
// ---------------------------------------------------------------------------
__global__ __launch_bounds__(512, 2) void mid1(
    const u16* __restrict__ x3, const u16* __restrict__ WqT,
    float* __restrict__ rsc2, const u16* __restrict__ tb,
    const u16* __restrict__ WvT, u16* __restrict__ vb)
{
  __shared__ u16 slds[4 * (8 * 1024 + 8192)];   // 128 KiB
  lds_u16* L = (lds_u16*)slds;
  const int bid = blockIdx.x;
  if (bid < 256) {
    const int nid = ((bid & 7) << 5) + (bid >> 3);
    gemm_body<6, 8>(L, nid & 1, nid >> 1, 0, x3, 1536, WqT, 512, rsc2, 1,
                    512, 0, 0, 0, nullptr, nullptr);
  } else {
    const int l = bid - 256;
    const int nid = ((l & 7) << 1) + (l >> 3);
    gemm_body<3, 8>(L, nid & 1, nid >> 1, 0, tb, 512, WvT, 512, vb, 512,
                    512, 0, 0, 0, nullptr, nullptr);
  }
}

// ---------------------------------------------------------------------------
// sim_topk: 256 blocks.  Main loop = sim GEMM (K=1536, MR4) with EPI7 LDS
// stash; then each of 8 waves processes 16 rows: top-8 select (+fp64 rescue
// if gap(5,6) < 2e-4), softmax, v-gather, gate, residual, LN2 -> yb.
// ---------------------------------------------------------------------------
__global__ __launch_bounds__(512, 2) void sim_topk(
    const u16* __restrict__ x3, const u16* __restrict__ wA,
    const u16* __restrict__ vb, const u16* __restrict__ xr2,
    const float* __restrict__ gate, const double* __restrict__ wtmpT,
    const float* __restrict__ rsc2, const float* __restrict__ ls,
    const float* __restrict__ g2, const float* __restrict__ b2,
    u16* __restrict__ yb)
{
  __shared__ u16 slds[65536];                   // 128 KiB (ring 96K | C 128K)
  lds_u16* L = (lds_u16*)slds;
  const int bid = blockIdx.x;
  const int nid = ((bid & 7) << 5) + (bid >> 3);
  const int by = nid & 31;
  const long zb = nid >> 5;

  gemm_body<7, 4>(L, 0, by, zb, x3, 1536, wA, 1536, nullptr, 0, 1536,
                  4096L * 1536, 256L * 1536, 0, nullptr, nullptr);
  __syncthreads();                              // stash complete

  const lds_f32* C = (const lds_f32*)L;
  const int lane = threadIdx.x & 63, wid = threadIdx.x >> 6;

  float g2r[8], b2r[8];
  *(float4*)&g2r[0] = *(const float4*)(g2 + lane * 8);
  *(float4*)&g2r[4] = *(const float4*)(g2 + lane * 8 + 4);
  *(float4*)&b2r[0] = *(const float4*)(b2 + lane * 8);
  *(float4*)&b2r[4] = *(const float4*)(b2 + lane * 8 + 4);
  const float lsv = __expf(ls[0]) * 0.044194173824159223f;
  const int b = (int)zb;

  for (int ir = 0; ir < 16; ++ir) {
    const int r = wid * 16 + ir;
    const long grow = zb * 4096 + by * 128 + r;

    const u16* xr = x3 + grow * 1536 + lane * 8;
    bf16x8 a0 = *(const bf16x8*)xr;
    bf16x8 a1 = *(const bf16x8*)(xr + 512);
    float xv[8];
#pragma unroll
    for (int j = 0; j < 8; ++j) xv[j] = btof((u16)a0[j]) + btof((u16)a1[j]);

    float vals[4];
#pragma unroll
    for (int i = 0; i < 4; ++i) vals[i] = C[r * 256 + lane + 64 * i];

    float topv[8]; int topi[8];
#pragma unroll
    for (int m = 0; m < 8; ++m) {
      float bv = vals[0]; int bl = 0;
      if (vals[1] > bv) { bv = vals[1]; bl = 1; }
      if (vals[2] > bv) { bv = vals[2]; bl = 2; }
      if (vals[3] > bv) { bv = vals[3]; bl = 3; }
      int bi = (bl << 6) | lane;       // token index = 64*bl + lane
#pragma unroll
      for (int off = 32; off; off >>= 1) {
        float ov = __shfl_xor(bv, off);
        int oi = __shfl_xor(bi, off);
        if (ov > bv || (ov == bv && oi < bi)) { bv = ov; bi = oi; }
      }
      topv[m] = bv; topi[m] = bi;
      if ((bi & 63) == lane) vals[bi >> 6] = -INFINITY;
    }

    if (topv[4] - topv[5] < 2e-4f) { // wave-uniform: fp64 re-rank of top-8
      bf16x8 a2 = *(const bf16x8*)(xr2 + grow * 512 + lane * 8);
      double xd[8];
#pragma unroll
      for (int j = 0; j < 8; ++j)
        xd[j] = (double)btof((u16)a0[j]) + (double)btof((u16)a1[j]) +
                (double)btof((u16)a2[j]);
      double cv[8]; int ti[8];
#pragma unroll
      for (int m = 0; m < 8; ++m) {
        const double* wp = wtmpT + ((long)b * 256 + topi[m]) * 512 + lane * 8;
        double a = 0.0;
#pragma unroll
        for (int j = 0; j < 8; ++j) a += xd[j] * wp[j];
#pragma unroll
        for (int off = 32; off; off >>= 1) a += __shfl_xor(a, off);
        cv[m] = a; ti[m] = topi[m];
      }
#define CE(i, jj) { \
      bool sw = (cv[jj] > cv[i]) || (cv[jj] == cv[i] && ti[jj] < ti[i]); \
      double tv = cv[i]; int tix = ti[i]; \
      cv[i] = sw ? cv[jj] : cv[i];  ti[i] = sw ? ti[jj] : ti[i]; \
      cv[jj] = sw ? tv : cv[jj];    ti[jj] = sw ? tix : ti[jj]; }
      CE(0,1) CE(2,3) CE(4,5) CE(6,7)
      CE(0,2) CE(1,3) CE(4,6) CE(5,7)
      CE(1,2) CE(5,6)
      CE(0,4) CE(1,5) CE(2,6) CE(3,7)
      CE(2,4) CE(3,5)
      CE(1,2) CE(3,4) CE(5,6)
#undef CE
#pragma unroll
      for (int m = 0; m < 5; ++m) { topv[m] = (float)cv[m]; topi[m] = ti[m]; }
    }

    const float rs = lsv * rsqrtf(rsc2[grow]);
    float e[5], se = 0.f;
#pragma unroll
    for (int m = 0; m < 5; ++m) {
      e[m] = __expf((topv[m] - topv[0]) * rs); se += e[m];
    }
    const float inv = 1.0f / se;
    const float g = gate[grow];

    float acc8[8] = {0, 0, 0, 0, 0, 0, 0, 0};
#pragma unroll
    for (int m = 0; m < 5; ++m) {
      const u16* vr = vb + ((long)b * 256 + topi[m]) * 512 + lane * 8;
      bf16x8 vv = *(const bf16x8*)vr;
      float wgt = e[m] * inv;
#pragma unroll
      for (int j = 0; j < 8; ++j) acc8[j] += wgt * btof((u16)vv[j]);
    }

    float y8[8]; float s = 0.f, sq = 0.f;
#pragma unroll
    for (int j = 0; j < 8; ++j) {
      y8[j] = xv[j] + acc8[j] * g;
      s += y8[j]; sq += y8[j] * y8[j];
    }
#pragma unroll
    for (int off = 32; off; off >>= 1) { s += __shfl_xor(s, off); sq += __shfl_xor(sq, off); }
    const float mu = s * (1.f / 512.f);
    const float var = sq * (1.f / 512.f) - mu * mu;
    const float rstd = 1.0f / sqrtf(var + 1e-5f);

    bf16x8 outp;
#pragma unroll
    for (int j = 0; j < 8; ++j)
      outp[j] = (short)f2b((y8[j] - mu) * rstd * g2r[j] + b2r[j]);
    *(bf16x8*)(yb + grow * 512 + lane * 8) = outp;
  }
}

// ---------------------------------------------------------------------------
// prep: one dispatch fusing (r15 form — wtilde NOT in here; r16 lesson:
// per-lane text-row streams were 16x uncoalesced + serial fp64 tail)
//   [0,640):    fp32->bf16 transposed weight copies (Wq,Wv,W1,W2)
//   [640,8832): LN1 -> x3=[x0|x1|x0], xr2, gate
//   [8832,9344): k-norm -> kT (token-normalized, c-major) + tb (bf16)
//   9344:       zero rsc2
// ---------------------------------------------------------------------------
__global__ __launch_bounds__(256) void prep_kernel(
    const float* __restrict__ vis, const float* __restrict__ text,
    const float* __restrict__ g1, const float* __restrict__ b1,
    const float* __restrict__ Wg, const float* __restrict__ bg,
    const float* __restrict__ Wq, const float* __restrict__ Wv,
    const float* __restrict__ W1, const float* __restrict__ W2,
    u16* __restrict__ x3, u16* __restrict__ xr2, float* __restrict__ gate,
    float* __restrict__ kT, u16* __restrict__ tb,
    u16* __restrict__ WqT, u16* __restrict__ WvT,
    u16* __restrict__ W1T, u16* __restrict__ W2T, float* __restrict__ rsc2)
{
  const int bid = blockIdx.x;
  const int lane = threadIdx.x & 63, wv = threadIdx.x >> 6;

  if (bid < 640) {                      // ---- weight transposes ----
    const float* src; u16* dst; int R, C, id, tilesX;
    if (bid < 64)       { src = Wq; dst = WqT; R = 512;  C = 512;  id = bid;       tilesX = 8; }
    else if (bid < 128) { src = Wv; dst = WvT; R = 512;  C = 512;  id = bid - 64;  tilesX = 8; }
    else if (bid < 384) { src = W1; dst = W1T; R = 512;  C = 2048; id = bid - 128; tilesX = 32; }
    else                { src = W2; dst = W2T; R = 2048; C = 512;  id = bid - 384; tilesX = 8; }
    const int c0 = (id % tilesX) * 64, r0 = (id / tilesX) * 64;
    __shared__ float t[64][65];
    const int tx = threadIdx.x & 63, ty = threadIdx.x >> 6;
    for (int j = ty; j < 64; j += 4)
      t[j][tx] = src[(long)(r0 + j) * C + c0 + tx];
    __syncthreads();
    for (int j = ty; j < 64; j += 4)
      dst[(long)(c0 + j) * R + r0 + tx] = f2b(t[tx][j]);
    return;
  }

  if (bid < 8832) {                     // ---- LN1 ----
    const long row = (long)(bid - 640) * 4 + wv;
    const float* src = vis + row * 512 + lane * 8;
    float v[8];
    *(float4*)&v[0] = *(const float4*)src;
    *(float4*)&v[4] = *(const float4*)(src + 4);
    float s = 0.f, sq = 0.f;
#pragma unroll
    for (int j = 0; j < 8; ++j) { s += v[j]; sq += v[j] * v[j]; }
#pragma unroll
    for (int off = 32; off; off >>= 1) { s += __shfl_xor(s, off); sq += __shfl_xor(sq, off); }
    const float mu = s * (1.f / 512.f);
    const float var = sq * (1.f / 512.f) - mu * mu;
    const float rstd = 1.0f / sqrtf(var + 1e-5f);

    float g1r[8], b1r[8], wgr[8];
    *(float4*)&g1r[0] = *(const float4*)(g1 + lane * 8);
    *(float4*)&g1r[4] = *(const float4*)(g1 + lane * 8 + 4);
    *(float4*)&b1r[0] = *(const float4*)(b1 + lane * 8);
    *(float4*)&b1r[4] = *(const float4*)(b1 + lane * 8 + 4);
    *(float4*)&wgr[0] = *(const float4*)(Wg + lane * 8);
    *(float4*)&wgr[4] = *(const float4*)(Wg + lane * 8 + 4);

    bf16x8 p0, p1, p2;
    float gd = 0.f;
#pragma unroll
    for (int j = 0; j < 8; ++j) {
      float d = (v[j] - mu) * rstd * g1r[j] + b1r[j];
      gd += d * wgr[j];
      u16 h0 = f2b(d);        float r1 = d - btof(h0);
      u16 h1 = f2b(r1);       float r2 = r1 - btof(h1);
      u16 h2 = f2b(r2);
      p0[j] = (short)h0; p1[j] = (short)h1; p2[j] = (short)h2;
    }
#pragma unroll
    for (int off = 32; off; off >>= 1) gd += __shfl_xor(gd, off);
    if (lane == 0) gate[row] = 1.0f / (1.0f + __expf(-(gd + bg[0])));

    u16* dst = x3 + row * 1536 + lane * 8;
    *(bf16x8*)dst = p0;
    *(bf16x8*)(dst + 512) = p1;
    *(bf16x8*)(dst + 1024) = p0;        // duplicate limb0 for sim K=1536
    *(bf16x8*)(xr2 + row * 512 + lane * 8) = p2;
    return;
  }

  if (bid < 9344) {                     // ---- k-norm -> kT + tb ----
    const long row = (long)(bid - 8832) * 4 + wv;   // 0..2047
    const int b = (int)(row >> 8), tok = (int)(row & 255);
    const float* src = text + row * 512 + lane * 8;
    float v[8];
    *(float4*)&v[0] = *(const float4*)src;
    *(float4*)&v[4] = *(const float4*)(src + 4);
    float sq = 0.f;
#pragma unroll
    for (int j = 0; j < 8; ++j) sq += v[j] * v[j];
#pragma unroll
    for (int off = 32; off; off >>= 1) sq += __shfl_xor(sq, off);
    const float inv = 1.0f / sqrtf(sq);
    bf16x8 pt;
    float* kdst = kT + (long)b * 131072 + tok;
#pragma unroll
    for (int j = 0; j < 8; ++j) {
      kdst[(long)(lane * 8 + j) * 256] = v[j] * inv;  // kT[b][c][tok]
      pt[j] = (short)f2b(v[j]);
    }
    *(bf16x8*)(tb + row * 512 + lane * 8) = pt;
    return;
  }

  // ---- zero rsc2 ----
  rsc2[threadIdx.x] = 0.f;
  rsc2[256 + threadIdx.x] = 0.f;
}

// ---------------------------------------------------------------------------
// w~ = Wq @ k^T in fp64 (coalesced kT column reads); writes wA = [w0|w0|w1]
// (B^T bf16, K=1536) and token-major fp64 wtmpT.
// ---------------------------------------------------------------------------
__global__ __launch_bounds__(256) void wtilde_kernel(
    const float* __restrict__ Wq, const float* __restrict__ kT,
    u16* __restrict__ wA, double* __restrict__ wtmpT)
{
  const int c0 = blockIdx.x * 4;
  const int b = blockIdx.y;
  __shared__ float wrow[4][512];
#pragma unroll
  for (int i = 0; i < 8; ++i) {
    int idx = threadIdx.x + i * 256;
    wrow[idx >> 9][idx & 511] = Wq[(long)c0 * 512 + idx];
  }
  __syncthreads();
  const int k = threadIdx.x;
  const float* kTb = kT + (long)b * 131072 + k;
  double a[4] = {0, 0, 0, 0};
  for (int j = 0; j < 512; ++j) {
    double kvd = (double)kTb[(long)j * 256];
    a[0] += (double)wrow[0][j] * kvd;
    a[1] += (double)wrow[1][j] * kvd;
    a[2] += (double)wrow[2][j] * kvd;
    a[3] += (double)wrow[3][j] * kvd;
  }
  const long kb = (long)b * 256 + k;
#pragma unroll
  for (int i = 0; i < 4; ++i) {
    const int c = c0 + i;
    u16 h0 = f2b((float)a[i]);  double r1 = a[i] - (double)btof(h0);
    u16 h1 = f2b((float)r1);
    wA[kb * 1536 + c] = h0;
    wA[kb * 1536 + 512 + c] = h0;
    wA[kb * 1536 + 1024 + c] = h1;
    wtmpT[kb * 512 + c] = a[i];
  }
}

// ---------------------------------------------------------------------------
extern "C" void kernel_launch(void* const* d_in, const int* in_sizes, int n_in,
                              void* d_out, int out_size, void* d_ws,
                              size_t ws_size, hipStream_t stream)
{
  const float* vis  = (const float*)d_in[0];
  const float* text = (const float*)d_in[1];
  const float* g1   = (const float*)d_in[2];
  const float* b1   = (const float*)d_in[3];
  const float* g2   = (const float*)d_in[4];
  const float* b2   = (const float*)d_in[5];
  const float* Wq   = (const float*)d_in[6];
  const float* Wv   = (const float*)d_in[7];
  const float* ls   = (const float*)d_in[8];
  const float* Wg   = (const float*)d_in[9];
  const float* bg   = (const float*)d_in[10];
  const float* W1   = (const float*)d_in[11];
  const float* bff1 = (const float*)d_in[12];
  const float* W2   = (const float*)d_in[13];
  const float* bff2 = (const float*)d_in[14];
  (void)in_sizes; (void)n_in; (void)out_size; (void)ws_size;

  char* w = (char*)d_ws;
  auto alloc = [&](size_t bytes) {
    char* p = w; w += (bytes + 255) & ~(size_t)255; return p;
  };
  u16* x3 = (u16*)alloc(134217728);
  u16* h = x3;
  char* gap = (char*)x3 + 100663296;            // 33.5MB free until FF1
  double* wtmpT = (double*)gap;                 // 8.4MB  [wtilde -> sim_topk]
  u16* wA = (u16*)(gap + 8388608);              // 6.3MB  [wtilde -> sim_topk]
  u16* yb = (u16*)alloc(33554432);
  u16* xr2 = (u16*)alloc(33554432);
  float* kT = (float*)alloc(4194304);
  u16* tb = (u16*)alloc(2097152);
  u16* vb = (u16*)alloc(2097152);
  u16* WqT = (u16*)alloc(524288);
  u16* WvT = (u16*)alloc(524288);
  u16* W1T = (u16*)alloc(2097152);
  u16* W2T = (u16*)alloc(2097152);
  float* gate = (float*)alloc(131072);
  float* rsc2 = (float*)alloc(131072);

  dim3 b256(256), b512(512);

  // prep: transposes + LN1 + knorm->kT + rsc2 zero (one dispatch)
  prep_kernel<<<9345, b256, 0, stream>>>(vis, text, g1, b1, Wg, bg, Wq, Wv,
                                         W1, W2, x3, xr2, gate, kT, tb, WqT,
                                         WvT, W1T, W2T, rsc2);

  // w~ = Wq@k^T (fp64, coalesced kT reads) -> wA + wtmpT
  wtilde_kernel<<<dim3(128, 8), b256, 0, stream>>>(Wq, kT, wA, wtmpT);

  // mid1: qnorm (256) + v-gemm (16) — completes rsc2/vb before sim_topk
  mid1<<<272, b512, 0, stream>>>(x3, WqT, rsc2, tb, WvT, vb);

  // sim GEMM fused with top-k/softmax/gather/LN2 -> yb
  sim_topk<<<256, b512, 0, stream>>>(x3, wA, vb, xr2, gate, wtmpT, rsc2, ls,
                                     g2, b2, yb);

  // FF1: h = gelu(y @ W1^T + bff1)  M=32768 N=2048 K=512
  gemm256<4, 8><<<dim3(8, 128, 1), b512, 0, stream>>>(
      yb, 512, W1T, 512, h, 2048, 512, 0, 0, 0, bff1, nullptr);
  // FF2: out = h @ W2^T + bff2 + y  M=32768 N=512 K=2048 -> fp32 d_out
  gemm256<5, 8><<<dim3(2, 128, 1), b512, 0, stream>>>(
      h, 2048, W2T, 2048, d_out, 512, 2048, 0, 0, 0, bff2, yb);
}

// Round 18
// 394.826 us; speedup vs baseline: 1.2440x; 1.0483x over previous
//
#include <hip/hip_runtime.h>
#include <hip/hip_bf16.h>

typedef unsigned short u16;
typedef float f32x4 __attribute__((ext_vector_type(4)));
typedef short bf16x8 __attribute__((ext_vector_type(8)));
typedef __attribute__((address_space(3))) u16 lds_u16;

#define DEV __device__ __forceinline__

DEV float btof(u16 u) { return __uint_as_float(((unsigned)u) << 16); }
DEV u16 f2b(float f) {                      // RNE fp32 -> bf16 (finite values)
  unsigned u = __float_as_uint(f);
  return (u16)((u + 0x7fffu + ((u >> 16) & 1u)) >> 16);
}
DEV void gld16(const void* g, lds_u16* l) { // async global->LDS, 16B per lane
  __builtin_amdgcn_global_load_lds(
      (const __attribute__((address_space(1))) void*)g,
      (__attribute__((address_space(3))) void*)l, 16, 0, 0);
}
// gelu(x) ~= x * sigmoid(2u), u = x*(0.79788456 + 0.03567741 x^2).  7 VALU.
DEV float gelu_fast(float x) {
  float xx = x * x;
  float p = fmaf(xx, -0.10294357f, -2.3022077f);
  float e; asm("v_exp_f32 %0, %1" : "=v"(e) : "v"(p * x));
  float r; asm("v_rcp_f32 %0, %1" : "=v"(r) : "v"(1.0f + e));
  return x * r;
}

#define LDSV(p) (*(const __attribute__((address_space(3))) bf16x8*)(p))

// ---------------------------------------------------------------------------
// Engine body (r13 config: 16x16x32 MFMA, zero bank conflicts, depth-2
// prefetch, counted vmcnt, 2 barriers/tile).  BM = MR*32, N-tile 256,
// BK=32; LDS ring of 4 bufs x (A[BM][32]+B[256][32]).
// EPI: 0 store f32 | 3 store bf16 | 4 gelu(acc+bias) bf16
//      5 acc+bias+res_bf16 -> f32 | 6 row-sum-of-squares atomic
// ---------------------------------------------------------------------------
template <int EPI, int MR>
DEV void gemm_body(lds_u16* LDS, int bx, int by, long z,
                   const u16* __restrict__ A, long lda,
                   const u16* __restrict__ B, long ldb,
                   void* __restrict__ Cv, long ldc, int K,
                   long sA, long sB, long sC,
                   const float* __restrict__ aux1,
                   const void* __restrict__ aux2)
{
  constexpr int SLOT = MR * 1024 + 8192;
  const int tid = threadIdx.x;
  const int lane = tid & 63, wid = tid >> 6;
  const int wm = wid >> 2, wn = wid & 3;
  const int qr = lane >> 4, qc = lane & 15;

  const long m0 = (long)by * (MR * 32), n0 = (long)bx << 8;
  const u16* Ab = A + z * sA;
  const u16* Bb = B + z * sB;
  const int T = K >> 5;           // K-tiles of 32 (multiple of 4 here)

  f32x4 acc[MR][4];
#pragma unroll
  for (int m = 0; m < MR; ++m)
#pragma unroll
    for (int n = 0; n < 4; ++n) acc[m][n] = (f32x4){0.f, 0.f, 0.f, 0.f};

  // B chunks (256 rows always): 2 x 16B per thread
  const int cb0 = wid * 128 + lane, cb1 = cb0 + 64;
  const int rb0 = cb0 >> 2, rb1 = cb1 >> 2;
  const int kb0off = ((cb0 & 3) ^ ((rb0 >> 1) & 3)) << 3;
  const int kb1off = ((cb1 & 3) ^ ((rb1 >> 1) & 3)) << 3;
  const u16* pb0 = Bb + (n0 + rb0) * ldb + kb0off;
  const u16* pb1 = Bb + (n0 + rb1) * ldb + kb1off;
  const int eb0 = cb0 * 8, eb1 = cb1 * 8;

  // A chunks: MR*128 chunks of 16B; MR==8: 2/thread, MR==4: 1/thread
  const int ca0 = (MR == 8) ? (wid * 128 + lane) : (wid * 64 + lane);
  const int ca1 = ca0 + 64;
  const int ra0 = ca0 >> 2, ra1 = ca1 >> 2;
  const int ka0off = ((ca0 & 3) ^ ((ra0 >> 1) & 3)) << 3;
  const int ka1off = ((ca1 & 3) ^ ((ra1 >> 1) & 3)) << 3;
  const u16* pa0 = Ab + (m0 + ra0) * lda + ka0off;
  const u16* pa1 = (MR == 8) ? (Ab + (m0 + ra1) * lda + ka1off) : pa0;
  const int ea0 = ca0 * 8, ea1 = ca1 * 8;

  const int swz = (qr ^ ((qc >> 1) & 3)) << 3;

  auto stageA = [&](int bsel, int so) {
    gld16(pa0 + so, LDS + bsel * SLOT + ea0);
    if constexpr (MR == 8) gld16(pa1 + so, LDS + bsel * SLOT + ea1);
  };
  auto stageB = [&](int bsel, int so) {
    gld16(pb0 + so, LDS + bsel * SLOT + MR * 1024 + eb0);
    gld16(pb1 + so, LDS + bsel * SLOT + MR * 1024 + eb1);
  };
  auto ldA4 = [&](bf16x8* dst, int bsel, int mh) {
#pragma unroll
    for (int mm = 0; mm < 4; ++mm) {
      const int rr = wm * (MR * 16) + (mh * 4 + mm) * 16 + qc;
      dst[mm] = LDSV(LDS + bsel * SLOT + rr * 32 + swz);
    }
  };
  auto ldB4 = [&](bf16x8* dst, int bsel) {
#pragma unroll
    for (int n = 0; n < 4; ++n) {
      const int rr = wn * 64 + n * 16 + qc;
      dst[n] = LDSV(LDS + bsel * SLOT + MR * 1024 + rr * 32 + swz);
    }
  };

  // prologue: stage tiles 0 and 1; pointers then at tile 2
  stageA(0, 0);  stageB(0, 0);
  stageA(1, 32); stageB(1, 32);
  pa0 += 64; pa1 += 64; pb0 += 64; pb1 += 64;

#define WAITV(N) asm volatile("s_waitcnt vmcnt(" #N ")" ::: "memory")
#define MFMAQ(MB) \
    __builtin_amdgcn_s_setprio(1); \
    _Pragma("unroll") \
    for (int mm = 0; mm < 4; ++mm) \
      _Pragma("unroll") \
      for (int n = 0; n < 4; ++n) \
        acc[MB + mm][n] = __builtin_amdgcn_mfma_f32_16x16x32_bf16( \
            a4[mm], b4[n], acc[MB + mm][n], 0, 0, 0); \
    __builtin_amdgcn_s_setprio(0);

#define TILE32(BUF, PF1, PF2, SO) { \
    bf16x8 a4[4], b4[4]; \
    if (PF2) { stageA((BUF + 2) & 3, SO); stageB((BUF + 2) & 3, SO); \
               if constexpr (MR == 8) { WAITV(8); } else { WAITV(6); } } \
    else if (PF1) { if constexpr (MR == 8) { WAITV(4); } else { WAITV(3); } } \
    else { WAITV(0); } \
    __builtin_amdgcn_s_barrier(); \
    ldA4(a4, BUF, 0); ldB4(b4, BUF); \
    MFMAQ(0) \
    if constexpr (MR == 8) { \
      ldA4(a4, BUF, 1); \
      MFMAQ(4) \
    } \
    asm volatile("s_waitcnt lgkmcnt(0)" ::: "memory"); \
    __builtin_amdgcn_s_barrier(); }

  for (int t2 = 0; t2 < T; t2 += 4) {
    const bool pfn = (t2 + 4 < T);
    TILE32(0, true, true, 0)
    TILE32(1, true, true, 32)
    TILE32(2, true, pfn, 64)
    TILE32(3, pfn, pfn, 96)
    pa0 += 128; pa1 += 128; pb0 += 128; pb1 += 128;
  }
#undef TILE32
#undef MFMAQ
#undef WAITV

  // epilogue: C/D layout col=lane&15, row=(lane>>4)*4+reg
  if constexpr (EPI == 6) {
    float* rsc2 = (float*)Cv;
#pragma unroll
    for (int m = 0; m < MR; ++m)
#pragma unroll
      for (int j = 0; j < 4; ++j) {
        float s = 0.f;
#pragma unroll
        for (int n = 0; n < 4; ++n) { float t2 = acc[m][n][j]; s = fmaf(t2, t2, s); }
        s += __shfl_xor(s, 1); s += __shfl_xor(s, 2);
        s += __shfl_xor(s, 4); s += __shfl_xor(s, 8);
        if (qc == 0)
          atomicAdd(rsc2 + (m0 + wm * (MR * 16) + m * 16 + qr * 4 + j), s);
      }
  } else {
#pragma unroll
    for (int m = 0; m < MR; ++m) {
#pragma unroll
      for (int n = 0; n < 4; ++n) {
        const long row0 = m0 + wm * (MR * 16) + m * 16 + qr * 4;
        const long col = n0 + wn * 64 + n * 16 + qc;
#pragma unroll
        for (int j = 0; j < 4; ++j) {
          const long idx = z * sC + (row0 + j) * ldc + col;
          float val = acc[m][n][j];
          if constexpr (EPI == 0) ((float*)Cv)[idx] = val;
          else if constexpr (EPI == 3) ((u16*)Cv)[idx] = f2b(val);
          else if constexpr (EPI == 4)
            ((u16*)Cv)[idx] = f2b(gelu_fast(val + aux1[col]));
          else if constexpr (EPI == 5) {
            float r = btof(((const u16*)aux2)[idx]);
            ((float*)Cv)[idx] = val + aux1[col] + r;
          }
        }
      }
    }
  }
}

// ---------------------------------------------------------------------------
// standalone wrapper (FF1 / FF2): XCD-swizzled grid + static LDS
// __launch_bounds__(512,2): arg2=min blocks/CU -> VGPR cap 128 (r7 lesson).
// ---------------------------------------------------------------------------
template <int EPI, int MR>
__global__ __launch_bounds__(512, 2) void gemm256(
    const u16* __restrict__ A, long lda, const u16* __restrict__ B, long ldb,
    void* __restrict__ Cv, long ldc, int K, long sA, long sB, long sC,
    const float* __restrict__ aux1, const void* __restrict__ aux2)
{
  __shared__ u16 lds[4 * (MR * 1024 + 8192)];
  const int gx = gridDim.x, gy = gridDim.y;
  const int nwg = gx * gy * (int)gridDim.z;
  const int orig = blockIdx.x + gx * (blockIdx.y + gy * blockIdx.z);
  const int nid = (orig & 7) * (nwg >> 3) + (orig >> 3);
  const int bx = nid % gx;
  const int rem1 = nid / gx;
  const int by = rem1 % gy;
  const long z = rem1 / gy;
  gemm_body<EPI, MR>((lds_u16*)lds, bx, by, z, A, lda, B, ldb, Cv, ldc, K,
                     sA, sB, sC, aux1, aux2);
}

// ---------------------------------------------------------------------------
// merged mid-GEMMs (one dispatch, 528 blocks; all depend only on
// prep+wtilde, mutually independent):
//   [0,256):   qnorm  EPI6 MR8: rsc2 += row-sumsq of x0@WqT  (M=32768 K=512)
//   [256,272): v-gemm EPI3 MR8: vb = bf16(text@WvT)          (M=2048  K=512)
//   [272,528): sim    EPI0 MR4: sim = x@wA^T  (K=1536, z=8, M=4096/batch)
// ---------------------------------------------------------------------------
__global__ __launch_bounds__(512, 2) void mid_gemms(
    const u16* __restrict__ x3, const u16* __restrict__ WqT,
    float* __restrict__ rsc2, const u16* __restrict__ tb,
    const u16* __restrict__ WvT, u16* __restrict__ vb,
    const u16* __restrict__ wA, float* __restrict__ sim)
{
  __shared__ u16 slds[4 * (8 * 1024 + 8192)];   // 128 KiB, max of all paths
  lds_u16* L = (lds_u16*)slds;
  const int bid = blockIdx.x;
  if (bid < 256) {
    const int nid = ((bid & 7) << 5) + (bid >> 3);
    gemm_body<6, 8>(L, nid & 1, nid >> 1, 0, x3, 1536, WqT, 512, rsc2, 1,
                    512, 0, 0, 0, nullptr, nullptr);
  } else if (bid < 272) {
    const int l = bid - 256;
    const int nid = ((l & 7) << 1) + (l >> 3);
    gemm_body<3, 8>(L, nid & 1, nid >> 1, 0, tb, 512, WvT, 512, vb, 512,
                    512, 0, 0, 0, nullptr, nullptr);
  } else {
    const int l = bid - 272;
    const int nid = ((l & 7) << 5) + (l >> 3);
    gemm_body<0, 4>(L, 0, nid & 31, nid >> 5, x3, 1536, wA, 1536, sim, 256,
                    1536, 4096L * 1536, 256L * 1536, 4096L * 256, nullptr,
                    nullptr);
  }
}

// ---------------------------------------------------------------------------
// prep: one dispatch fusing
//   [0,640):    fp32->bf16 transposed weight copies (Wq,Wv,W1,W2)
//   [640,8832): LN1 -> x3=[x0|x1|x0], xr2, gate
//   [8832,9344): k-norm -> kT (token-normalized, c-major) + tb (bf16)
//   9344:       zero rsc2
// ---------------------------------------------------------------------------
__global__ __launch_bounds__(256) void prep_kernel(
    const float* __restrict__ vis, const float* __restrict__ text,
    const float* __restrict__ g1, const float* __restrict__ b1,
    const float* __restrict__ Wg, const float* __restrict__ bg,
    const float* __restrict__ Wq, const float* __restrict__ Wv,
    const float* __restrict__ W1, const float* __restrict__ W2,
    u16* __restrict__ x3, u16* __restrict__ xr2, float* __restrict__ gate,
    float* __restrict__ kT, u16* __restrict__ tb,
    u16* __restrict__ WqT, u16* __restrict__ WvT,
    u16* __restrict__ W1T, u16* __restrict__ W2T, float* __restrict__ rsc2)
{
  const int bid = blockIdx.x;
  const int lane = threadIdx.x & 63, wv = threadIdx.x >> 6;

  if (bid < 640) {                      // ---- weight transposes ----
    const float* src; u16* dst; int R, C, id, tilesX;
    if (bid < 64)       { src = Wq; dst = WqT; R = 512;  C = 512;  id = bid;       tilesX = 8; }
    else if (bid < 128) { src = Wv; dst = WvT; R = 512;  C = 512;  id = bid - 64;  tilesX = 8; }
    else if (bid < 384) { src = W1; dst = W1T; R = 512;  C = 2048; id = bid - 128; tilesX = 32; }
    else                { src = W2; dst = W2T; R = 2048; C = 512;  id = bid - 384; tilesX = 8; }
    const int c0 = (id % tilesX) * 64, r0 = (id / tilesX) * 64;
    __shared__ float t[64][65];
    const int tx = threadIdx.x & 63, ty = threadIdx.x >> 6;
    for (int j = ty; j < 64; j += 4)
      t[j][tx] = src[(long)(r0 + j) * C + c0 + tx];
    __syncthreads();
    for (int j = ty; j < 64; j += 4)
      dst[(long)(c0 + j) * R + r0 + tx] = f2b(t[tx][j]);
    return;
  }

  if (bid < 8832) {                     // ---- LN1 ----
    const long row = (long)(bid - 640) * 4 + wv;
    const float* src = vis + row * 512 + lane * 8;
    float v[8];
    *(float4*)&v[0] = *(const float4*)src;
    *(float4*)&v[4] = *(const float4*)(src + 4);
    float s = 0.f, sq = 0.f;
#pragma unroll
    for (int j = 0; j < 8; ++j) { s += v[j]; sq += v[j] * v[j]; }
#pragma unroll
    for (int off = 32; off; off >>= 1) { s += __shfl_xor(s, off); sq += __shfl_xor(sq, off); }
    const float mu = s * (1.f / 512.f);
    const float var = sq * (1.f / 512.f) - mu * mu;
    const float rstd = 1.0f / sqrtf(var + 1e-5f);

    float g1r[8], b1r[8], wgr[8];
    *(float4*)&g1r[0] = *(const float4*)(g1 + lane * 8);
    *(float4*)&g1r[4] = *(const float4*)(g1 + lane * 8 + 4);
    *(float4*)&b1r[0] = *(const float4*)(b1 + lane * 8);
    *(float4*)&b1r[4] = *(const float4*)(b1 + lane * 8 + 4);
    *(float4*)&wgr[0] = *(const float4*)(Wg + lane * 8);
    *(float4*)&wgr[4] = *(const float4*)(Wg + lane * 8 + 4);

    bf16x8 p0, p1, p2;
    float gd = 0.f;
#pragma unroll
    for (int j = 0; j < 8; ++j) {
      float d = (v[j] - mu) * rstd * g1r[j] + b1r[j];
      gd += d * wgr[j];
      u16 h0 = f2b(d);        float r1 = d - btof(h0);
      u16 h1 = f2b(r1);       float r2 = r1 - btof(h1);
      u16 h2 = f2b(r2);
      p0[j] = (short)h0; p1[j] = (short)h1; p2[j] = (short)h2;
    }
#pragma unroll
    for (int off = 32; off; off >>= 1) gd += __shfl_xor(gd, off);
    if (lane == 0) gate[row] = 1.0f / (1.0f + __expf(-(gd + bg[0])));

    u16* dst = x3 + row * 1536 + lane * 8;
    *(bf16x8*)dst = p0;
    *(bf16x8*)(dst + 512) = p1;
    *(bf16x8*)(dst + 1024) = p0;        // duplicate limb0 for sim K=1536
    *(bf16x8*)(xr2 + row * 512 + lane * 8) = p2;
    return;
  }

  if (bid < 9344) {                     // ---- k-norm -> kT + tb ----
    const long row = (long)(bid - 8832) * 4 + wv;   // 0..2047
    const int b = (int)(row >> 8), tok = (int)(row & 255);
    const float* src = text + row * 512 + lane * 8;
    float v[8];
    *(float4*)&v[0] = *(const float4*)src;
    *(float4*)&v[4] = *(const float4*)(src + 4);
    float sq = 0.f;
#pragma unroll
    for (int j = 0; j < 8; ++j) sq += v[j] * v[j];
#pragma unroll
    for (int off = 32; off; off >>= 1) sq += __shfl_xor(sq, off);
    const float inv = 1.0f / sqrtf(sq);
    bf16x8 pt;
    float* kdst = kT + (long)b * 131072 + tok;
#pragma unroll
    for (int j = 0; j < 8; ++j) {
      kdst[(long)(lane * 8 + j) * 256] = v[j] * inv;  // kT[b][c][tok]
      pt[j] = (short)f2b(v[j]);
    }
    *(bf16x8*)(tb + row * 512 + lane * 8) = pt;
    return;
  }

  // ---- zero rsc2 ----
  rsc2[threadIdx.x] = 0.f;
  rsc2[256 + threadIdx.x] = 0.f;
}

// ---------------------------------------------------------------------------
// w~ = Wq @ k^T in fp64 (coalesced kT column reads); writes wA = [w0|w0|w1]
// (B^T bf16, K=1536) and token-major fp64 wtmpT.
// ---------------------------------------------------------------------------
__global__ __launch_bounds__(256) void wtilde_kernel(
    const float* __restrict__ Wq, const float* __restrict__ kT,
    u16* __restrict__ wA, double* __restrict__ wtmpT)
{
  const int c0 = blockIdx.x * 4;
  const int b = blockIdx.y;
  __shared__ float wrow[4][512];
#pragma unroll
  for (int i = 0; i < 8; ++i) {
    int idx = threadIdx.x + i * 256;
    wrow[idx >> 9][idx & 511] = Wq[(long)c0 * 512 + idx];
  }
  __syncthreads();
  const int k = threadIdx.x;
  const float* kTb = kT + (long)b * 131072 + k;
  double a[4] = {0, 0, 0, 0};
  for (int j = 0; j < 512; ++j) {
    double kvd = (double)kTb[(long)j * 256];
    a[0] += (double)wrow[0][j] * kvd;
    a[1] += (double)wrow[1][j] * kvd;
    a[2] += (double)wrow[2][j] * kvd;
    a[3] += (double)wrow[3][j] * kvd;
  }
  const long kb = (long)b * 256 + k;
#pragma unroll
  for (int i = 0; i < 4; ++i) {
    const int c = c0 + i;
    u16 h0 = f2b((float)a[i]);  double r1 = a[i] - (double)btof(h0);
    u16 h1 = f2b((float)r1);
    wA[kb * 1536 + c] = h0;
    wA[kb * 1536 + 512 + c] = h0;
    wA[kb * 1536 + 1024 + c] = h1;
    wtmpT[kb * 512 + c] = a[i];
  }
}

// ---------------------------------------------------------------------------
// fused: top-8 on raw sim; if gap(5,6) < tau=2e-4, fp64 re-rank of the 8
// candidates only; row scale from rsc2 inline; softmax(5), gather v, gate,
// residual, LN2 -> y (bf16).  wave per row (8192 blocks: TLP for the
// latency-bound selection chains — r17 lesson: do NOT fuse into few blocks).
// ---------------------------------------------------------------------------
__global__ __launch_bounds__(256) void topk_fuse(
    const float* __restrict__ sim, const u16* __restrict__ v,
    const u16* __restrict__ x3, const u16* __restrict__ xr2,
    const float* __restrict__ gate, const double* __restrict__ wtmpT,
    const float* __restrict__ rsc2, const float* __restrict__ ls,
    const float* __restrict__ g2, const float* __restrict__ b2,
    u16* __restrict__ yb)
{
  const int lane = threadIdx.x & 63, wv = threadIdx.x >> 6;
  const long row = (long)blockIdx.x * 4 + wv;
  const int b = (int)(row >> 12);

  const u16* xr = x3 + row * 1536 + lane * 8;
  bf16x8 a0 = *(const bf16x8*)xr;
  bf16x8 a1 = *(const bf16x8*)(xr + 512);
  float xv[8];
#pragma unroll
  for (int j = 0; j < 8; ++j) xv[j] = btof((u16)a0[j]) + btof((u16)a1[j]);

  float4 sv = *(const float4*)(sim + row * 256 + lane * 4);
  float vals[4] = {sv.x, sv.y, sv.z, sv.w};
  float topv[8]; int topi[8];
#pragma unroll
  for (int m = 0; m < 8; ++m) {
    float bv = vals[0]; int bl = 0;
    if (vals[1] > bv) { bv = vals[1]; bl = 1; }
    if (vals[2] > bv) { bv = vals[2]; bl = 2; }
    if (vals[3] > bv) { bv = vals[3]; bl = 3; }
    int bi = lane * 4 + bl;
#pragma unroll
    for (int off = 32; off; off >>= 1) {
      float ov = __shfl_xor(bv, off);
      int oi = __shfl_xor(bi, off);
      if (ov > bv || (ov == bv && oi < bi)) { bv = ov; bi = oi; }
    }
    topv[m] = bv; topi[m] = bi;
    if ((bi >> 2) == lane) {
      int tt = bi & 3;
      if (tt == 0) vals[0] = -INFINITY; else if (tt == 1) vals[1] = -INFINITY;
      else if (tt == 2) vals[2] = -INFINITY; else vals[3] = -INFINITY;
    }
  }

  if (topv[4] - topv[5] < 2e-4f) {   // wave-uniform: fp64 re-rank of top-8
    bf16x8 a2 = *(const bf16x8*)(xr2 + row * 512 + lane * 8);
    double xd[8];
#pragma unroll
    for (int j = 0; j < 8; ++j)
      xd[j] = (double)btof((u16)a0[j]) + (double)btof((u16)a1[j]) +
              (double)btof((u16)a2[j]);
    double cv[8]; int ti[8];
#pragma unroll
    for (int m = 0; m < 8; ++m) {
      const double* wp = wtmpT + ((long)b * 256 + topi[m]) * 512 + lane * 8;
      double a = 0.0;
#pragma unroll
      for (int j = 0; j < 8; ++j) a += xd[j] * wp[j];
#pragma unroll
      for (int off = 32; off; off >>= 1) a += __shfl_xor(a, off);
      cv[m] = a; ti[m] = topi[m];
    }
#define CE(i, jj) { \
    bool sw = (cv[jj] > cv[i]) || (cv[jj] == cv[i] && ti[jj] < ti[i]); \
    double tv = cv[i]; int tix = ti[i]; \
    cv[i] = sw ? cv[jj] : cv[i];  ti[i] = sw ? ti[jj] : ti[i]; \
    cv[jj] = sw ? tv : cv[jj];    ti[jj] = sw ? tix : ti[jj]; }
    CE(0,1) CE(2,3) CE(4,5) CE(6,7)
    CE(0,2) CE(1,3) CE(4,6) CE(5,7)
    CE(1,2) CE(5,6)
    CE(0,4) CE(1,5) CE(2,6) CE(3,7)
    CE(2,4) CE(3,5)
    CE(1,2) CE(3,4) CE(5,6)
#undef CE
#pragma unroll
    for (int m = 0; m < 5; ++m) { topv[m] = (float)cv[m]; topi[m] = ti[m]; }
  }

  const float rs = __expf(ls[0]) * 0.044194173824159223f * rsqrtf(rsc2[row]);
  float e[5], se = 0.f;
#pragma unroll
  for (int m = 0; m < 5; ++m) {
    e[m] = __expf((topv[m] - topv[0]) * rs); se += e[m];
  }
  const float inv = 1.0f / se;
  const float g = gate[row];

  float acc8[8] = {0, 0, 0, 0, 0, 0, 0, 0};
#pragma unroll
  for (int m = 0; m < 5; ++m) {
    const u16* vr = v + ((long)b * 256 + topi[m]) * 512 + lane * 8;
    bf16x8 vv = *(const bf16x8*)vr;
    float wgt = e[m] * inv;
#pragma unroll
    for (int j = 0; j < 8; ++j) acc8[j] += wgt * btof((u16)vv[j]);
  }

  float y8[8]; float s = 0.f, sq = 0.f;
#pragma unroll
  for (int j = 0; j < 8; ++j) {
    y8[j] = xv[j] + acc8[j] * g;
    s += y8[j]; sq += y8[j] * y8[j];
  }
#pragma unroll
  for (int off = 32; off; off >>= 1) { s += __shfl_xor(s, off); sq += __shfl_xor(sq, off); }
  const float mu = s * (1.f / 512.f);
  const float var = sq * (1.f / 512.f) - mu * mu;
  const float rstd = 1.0f / sqrtf(var + 1e-5f);

  float g2r[8], b2r[8];
  *(float4*)&g2r[0] = *(const float4*)(g2 + lane * 8);
  *(float4*)&g2r[4] = *(const float4*)(g2 + lane * 8 + 4);
  *(float4*)&b2r[0] = *(const float4*)(b2 + lane * 8);
  *(float4*)&b2r[4] = *(const float4*)(b2 + lane * 8 + 4);
  bf16x8 outp;
#pragma unroll
  for (int j = 0; j < 8; ++j)
    outp[j] = (short)f2b((y8[j] - mu) * rstd * g2r[j] + b2r[j]);
  *(bf16x8*)(yb + row * 512 + lane * 8) = outp;
}

// ---------------------------------------------------------------------------
extern "C" void kernel_launch(void* const* d_in, const int* in_sizes, int n_in,
                              void* d_out, int out_size, void* d_ws,
                              size_t ws_size, hipStream_t stream)
{
  const float* vis  = (const float*)d_in[0];
  const float* text = (const float*)d_in[1];
  const float* g1   = (const float*)d_in[2];
  const float* b1   = (const float*)d_in[3];
  const float* g2   = (const float*)d_in[4];
  const float* b2   = (const float*)d_in[5];
  const float* Wq   = (const float*)d_in[6];
  const float* Wv   = (const float*)d_in[7];
  const float* ls   = (const float*)d_in[8];
  const float* Wg   = (const float*)d_in[9];
  const float* bg   = (const float*)d_in[10];
  const float* W1   = (const float*)d_in[11];
  const float* bff1 = (const float*)d_in[12];
  const float* W2   = (const float*)d_in[13];
  const float* bff2 = (const float*)d_in[14];
  (void)in_sizes; (void)n_in; (void)out_size; (void)ws_size;

  char* w = (char*)d_ws;
  auto alloc = [&](size_t bytes) {
    char* p = w; w += (bytes + 255) & ~(size_t)255; return p;
  };
  u16* x3 = (u16*)alloc(134217728);
  u16* h = x3;
  char* gap = (char*)x3 + 100663296;            // 33.5MB free until FF1
  double* wtmpT = (double*)gap;                 // 8.4MB  [wtilde -> topk]
  u16* wA = (u16*)(gap + 8388608);              // 6.3MB  [wtilde -> sim]
  float* sim = (float*)alloc(33554432);
  u16* yb = (u16*)alloc(33554432);
  u16* xr2 = (u16*)alloc(33554432);
  float* kT = (float*)alloc(4194304);
  u16* tb = (u16*)alloc(2097152);
  u16* vb = (u16*)alloc(2097152);
  u16* WqT = (u16*)alloc(524288);
  u16* WvT = (u16*)alloc(524288);
  u16* W1T = (u16*)alloc(2097152);
  u16* W2T = (u16*)alloc(2097152);
  float* gate = (float*)alloc(131072);
  float* rsc2 = (float*)alloc(131072);

  dim3 b256(256), b512(512);

  // prep: transposes + LN1 + knorm->kT + rsc2 zero (one dispatch)
  prep_kernel<<<9345, b256, 0, stream>>>(vis, text, g1, b1, Wg, bg, Wq, Wv,
                                         W1, W2, x3, xr2, gate, kT, tb, WqT,
                                         WvT, W1T, W2T, rsc2);

  // w~ = Wq@k^T (fp64) -> wA + wtmpT directly
  wtilde_kernel<<<dim3(128, 8), b256, 0, stream>>>(Wq, kT, wA, wtmpT);

  // merged: qnorm (256 blocks) + v-gemm (16) + sim (256) in one dispatch
  mid_gemms<<<528, b512, 0, stream>>>(x3, WqT, rsc2, tb, WvT, vb, wA, sim);

  topk_fuse<<<8192, b256, 0, stream>>>(sim, vb, x3, xr2, gate, wtmpT, rsc2,
                                       ls, g2, b2, yb);

  // FF1: h = gelu(y @ W1^T + bff1)  M=32768 N=2048 K=512
  gemm256<4, 8><<<dim3(8, 128, 1), b512, 0, stream>>>(
      yb, 512, W1T, 512, h, 2048, 512, 0, 0, 0, bff1, nullptr);
  // FF2: out = h @ W2^T + bff2 + y  M=32768 N=512 K=2048 -> fp32 d_out
  gemm256<5, 8><<<dim3(2, 128, 1), b512, 0, stream>>>(
      h, 2048, W2T, 2048, d_out, 512, 2048, 0, 0, 0, bff2, yb);
}